// Round 7
// baseline (210.825 us; speedup 1.0000x reference)
//
#include <hip/hip_runtime.h>
#include <math.h>

// Binned-sufficient-statistics Newton solver, wave64 edition.
//  - bin_kernel: (t,y) -> 1024 fine bins x 7 fp32 stats; 256 blocks x 1024
//    threads (16 waves/CU for latency hiding); flush into 4 replicated
//    global stat buffers (blockIdx&3) to cut atomic contention.
//  - gn_kernel: 1 block x 64 threads, 64 coarse bins (one per lane, 4th-order
//    Taylor), full-Newton + Armijo with MERGED moment pass (the accepted
//    trial's 15 moments are reused as the next iteration's gradient basis).

#define FBINS 1024
#define NST   7
#define TMAXF 5.0f
#define BIN_BLOCKS  256
#define BIN_THREADS 1024
#define MAXREPL 4
#define CB    64
#define CPL   (FBINS / CB)   // 16 fine bins per coarse bin

// ---------------------------------------------------------------- fast fp64 math
__device__ __forceinline__ double fexp(double x) {
  x = fmin(fmax(x, -708.0), 700.0);
  const double L2E   = 1.4426950408889634074;
  const double LN2HI = 6.93147180369123816490e-01;
  const double LN2LO = 1.90821492927058770002e-10;
  double fn = rint(x * L2E);
  double r  = fma(-fn, LN2HI, x);
  r = fma(-fn, LN2LO, r);
  double p = 2.505210838544172e-8;            // 1/11!
  p = fma(p, r, 2.755731922398589e-7);
  p = fma(p, r, 2.7557319223985893e-6);
  p = fma(p, r, 2.48015873015873e-5);
  p = fma(p, r, 1.984126984126984e-4);
  p = fma(p, r, 1.3888888888888889e-3);
  p = fma(p, r, 8.333333333333333e-3);
  p = fma(p, r, 4.1666666666666664e-2);
  p = fma(p, r, 1.6666666666666666e-1);
  p = fma(p, r, 0.5);
  p = fma(p, r, 1.0);
  p = fma(p, r, 1.0);
  long long n = (long long)fn;
  double s = __longlong_as_double((n + 1023LL) << 52);
  return p * s;
}

__device__ __forceinline__ double flog_ge1(double w) {  // w >= 1
  long long bits = __double_as_longlong(w);
  int k = (int)((bits >> 52) & 0x7FF) - 1023;
  double m = __longlong_as_double((bits & 0xFFFFFFFFFFFFFLL) | 0x3FF0000000000000LL);
  if (m > 1.4142135623730951) { m *= 0.5; k += 1; }
  double t  = (m - 1.0) / (m + 1.0);
  double t2 = t * t;
  double p = 1.0 / 13.0;
  p = fma(p, t2, 1.0 / 11.0);
  p = fma(p, t2, 1.0 / 9.0);
  p = fma(p, t2, 1.0 / 7.0);
  p = fma(p, t2, 0.2);
  p = fma(p, t2, 1.0 / 3.0);
  p = fma(p, t2, 1.0);
  p = 2.0 * t * p;
  return fma((double)k, 6.93147180559945309417e-01, p);
}

__device__ __forceinline__ double sp_fast(double u)  { return flog_ge1(1.0 + fexp(u)); }
__device__ __forceinline__ double sig_fast(double u) { return 1.0 / (1.0 + fexp(-u)); }

// butterfly: every lane ends with the full 64-lane sum (bitwise-uniform)
__device__ __forceinline__ double bred(double v) {
  for (int m = 1; m < 64; m <<= 1) v += __shfl_xor(v, m, 64);
  return v;
}

// ---------------------------------------------------------------- binning
__global__ void zero_stats(float* __restrict__ s, int nfloats) {
  int i = blockIdx.x * blockDim.x + threadIdx.x;
  if (i < nfloats) s[i] = 0.0f;
}

__device__ __forceinline__ void bin_point(float* sb, float ti, float yi) {
  int b = (int)(ti * ((float)FBINS / TMAXF));
  b = b < 0 ? 0 : (b > FBINS - 1 ? FBINS - 1 : b);
  float c  = (b + 0.5f) * (TMAXF / (float)FBINS);
  float d  = ti - c;
  float d2 = d * d;
  atomicAdd(&sb[0 * FBINS + b], 1.0f);
  atomicAdd(&sb[1 * FBINS + b], d);
  atomicAdd(&sb[2 * FBINS + b], d2);
  atomicAdd(&sb[3 * FBINS + b], d2 * d);
  atomicAdd(&sb[4 * FBINS + b], yi);
  atomicAdd(&sb[5 * FBINS + b], yi * d);
  atomicAdd(&sb[6 * FBINS + b], yi * d2);
}

__global__ __launch_bounds__(BIN_THREADS)
void bin_kernel(const float* __restrict__ y, const float* __restrict__ t,
                int n, float* __restrict__ stats, int repl) {
  __shared__ float sb[NST * FBINS];   // 28 KB
  for (int i = threadIdx.x; i < NST * FBINS; i += blockDim.x) sb[i] = 0.0f;
  __syncthreads();
  int gtid = blockIdx.x * blockDim.x + threadIdx.x;
  int nt   = gridDim.x * blockDim.x;
  int nv   = n >> 2;
  const float4* t4 = (const float4*)t;
  const float4* y4 = (const float4*)y;
  for (int i = gtid; i < nv; i += nt) {
    float4 tv = t4[i], yv = y4[i];
    bin_point(sb, tv.x, yv.x);
    bin_point(sb, tv.y, yv.y);
    bin_point(sb, tv.z, yv.z);
    bin_point(sb, tv.w, yv.w);
  }
  for (int i = (nv << 2) + gtid; i < n; i += nt) bin_point(sb, t[i], y[i]);
  __syncthreads();
  float* dst = stats + (size_t)(blockIdx.x & (repl - 1)) * (NST * FBINS);
  for (int i = threadIdx.x; i < NST * FBINS; i += blockDim.x) {
    float v = sb[i];
    if (v != 0.0f) atomicAdd(&dst[i], v);
  }
}

// ---------------------------------------------------------------- solver
template <bool FUSED>
__global__ __launch_bounds__(64)
void gn_kernel(const float* __restrict__ stats_g, int repl,
               const float* __restrict__ yv, const float* __restrict__ tv, int n,
               const float* __restrict__ log_mu_p,
               const float* __restrict__ x_init_p,
               float* __restrict__ out) {
  const int lane = threadIdx.x;

  __shared__ float sbin[FUSED ? NST * FBINS : 1];
  const float* stats = stats_g;
  if (FUSED) {   // safety net only (ws < 28 KB)
    for (int i = lane; i < NST * FBINS; i += 64) sbin[i] = 0.0f;
    __syncthreads();
    for (int i = lane; i < n; i += 64) bin_point(sbin, tv[i], yv[i]);
    __syncthreads();
    stats = sbin;
    repl = 1;
  }

  // ---- collapse 16 fine bins -> 1 coarse bin per lane (4th-order stats) ----
  const double hf = 5.0 / 1024.0;          // exact in fp64/fp32
  double cn = 0, cb1 = 0, cb2 = 0, cb3 = 0, cb4 = 0;
  double cy = 0, cy1 = 0, cy2 = 0, cy3 = 0;
  const int base = lane * CPL;
#pragma unroll
  for (int i = 0; i < CPL; ++i) {
    double nf = 0, d1 = 0, d2 = 0, d3 = 0, yf = 0, y1 = 0, y2 = 0;
    for (int r = 0; r < repl; ++r) {
      const float* st = stats + (size_t)r * (NST * FBINS);
      nf += (double)st[0 * FBINS + base + i];
      d1 += (double)st[1 * FBINS + base + i];
      d2 += (double)st[2 * FBINS + base + i];
      d3 += (double)st[3 * FBINS + base + i];
      yf += (double)st[4 * FBINS + base + i];
      y1 += (double)st[5 * FBINS + base + i];
      y2 += (double)st[6 * FBINS + base + i];
    }
    double dl  = ((double)i - 7.5) * hf;   // fine center - coarse center, exact
    double dl2 = dl * dl, dl3 = dl2 * dl, dl4 = dl2 * dl2;
    cn  += nf;
    cb1 += d1 + dl * nf;
    cb2 += d2 + 2.0 * dl * d1 + dl2 * nf;
    cb3 += d3 + 3.0 * dl * d2 + 3.0 * dl2 * d1 + dl3 * nf;
    cb4 += 4.0 * dl * d3 + 6.0 * dl2 * d2 + 4.0 * dl3 * d1 + dl4 * nf;
    cy  += yf;
    cy1 += y1 + dl * yf;
    cy2 += y2 + 2.0 * dl * y1 + dl2 * yf;
    cy3 += 3.0 * dl * y2 + 3.0 * dl2 * y1 + dl3 * yf;
  }
  const double cc = (double)(base + 8) * hf;   // coarse bin center, exact

  // ---- canary: total count ----
  {
    double tot = bred(cn);
    if (fabs(tot - (double)n) > (double)n * 1e-3 + 1.0) {
      if (lane == 0) for (int j = 0; j < 4; ++j) out[j] = 20.0f + (float)j;
      return;
    }
  }

  // full 15-moment pass at (l0,l1); all lanes end with global sums
  auto moments15 = [&](double l0, double l1, double* mom) {
    double E0 = fexp(-l0 * cc), E1 = fexp(-l1 * cc);
    double AA[3] = {E0 * E0, E0 * E1, E1 * E1};
    double MM[3] = {2.0 * l0, l0 + l1, 2.0 * l1};
#pragma unroll
    for (int q = 0; q < 3; ++q) {
      double m  = MM[q];
      double q0 = cn + m * (-cb1 + m * (0.5 * cb2 + m * (-(1.0/6.0) * cb3 + m * (1.0/24.0) * cb4)));
      double q1 = cb1 + m * (-cb2 + m * (0.5 * cb3 - m * (1.0/6.0) * cb4));
      double q2 = cb2 + m * (-cb3 + m * 0.5 * cb4);
      mom[q * 3 + 0] = AA[q] * q0;
      mom[q * 3 + 1] = AA[q] * (cc * q0 + q1);
      mom[q * 3 + 2] = AA[q] * (cc * (cc * q0 + 2.0 * q1) + q2);
    }
    {
      double r0 = cy + l0 * (-cy1 + l0 * (0.5 * cy2 - l0 * (1.0/6.0) * cy3));
      double r1 = cy1 + l0 * (-cy2 + 0.5 * l0 * cy3);
      double r2 = cy2 - l0 * cy3;
      mom[9]  = E0 * r0;
      mom[10] = E0 * (cc * r0 + r1);
      mom[11] = E0 * (cc * (cc * r0 + 2.0 * r1) + r2);
      r0 = cy + l1 * (-cy1 + l1 * (0.5 * cy2 - l1 * (1.0/6.0) * cy3));
      r1 = cy1 + l1 * (-cy2 + 0.5 * l1 * cy3);
      r2 = cy2 - l1 * cy3;
      mom[12] = E1 * r0;
      mom[13] = E1 * (cc * r0 + r1);
      mom[14] = E1 * (cc * (cc * r0 + 2.0 * r1) + r2);
    }
#pragma unroll
    for (int k = 0; k < 15; ++k) mom[k] = bred(mom[k]);
  };

  // ---- init (all lanes redundantly; uniform) ----
  const double mu = exp((double)log_mu_p[0]);
  double u0, u1, u2, u3;
  {
    double v0 = fmax((double)x_init_p[0], 1e-3);
    double v1 = fmax((double)x_init_p[1], 1e-3);
    double v2 = fmax((double)x_init_p[2], 1e-3);
    double v3 = fmax((double)x_init_p[3], 1e-3);
    u0 = log(exp(v0) - 1.0 + 1e-8);
    u1 = log(exp(v1) - 1.0 + 1e-8);
    u2 = log(exp(v2) - 1.0 + 1e-8);
    u3 = log(exp(v3) - 1.0 + 1e-8);
  }
  double x0 = sp_fast(u0), x1 = sp_fast(u1), x2 = sp_fast(u2), x3 = sp_fast(u3);

  double mom[15];
  moments15(x2, x3, mom);

  for (int iter = 0; iter < 300; ++iter) {
    double Sa = mom[0],  T1a = mom[1],  T2a = mom[2];
    double Sab= mom[3],  T1ab= mom[4],  T2ab= mom[5];
    double Sb = mom[6],  T1b = mom[7],  T2b = mom[8];
    double Y0a= mom[9],  Y1a = mom[10], Y2a = mom[11];
    double Y0b= mom[12], Y1b = mom[13], Y2b = mom[14];

    // ---- Newton system (all lanes redundantly) ----
    double sd0 = sig_fast(u0), sd1 = sig_fast(u1), sd2 = sig_fast(u2), sd3 = sig_fast(u3);
    double c0 = x0, c1 = x1;

    double gx0 = -Y0a + c0 * Sa  + c1 * Sab;
    double gx1 = -Y0b + c0 * Sab + c1 * Sb;
    double gx2 = c0 * (Y1a - c0 * T1a  - c1 * T1ab);
    double gx3 = c1 * (Y1b - c0 * T1ab - c1 * T1b);

    double sdv[4] = {sd0, sd1, sd2, sd3};
    double gxv[4] = {gx0 + mu * x0, gx1 + mu * x1, gx2 + mu * x2, gx3 + mu * x3};
    double gv[4];
#pragma unroll
    for (int i = 0; i < 4; ++i) gv[i] = gxv[i] * sdv[i];

    double Hx[4][4];
    Hx[0][0] = Sa;   Hx[0][1] = Sab;
    Hx[0][2] = Y1a - 2.0 * c0 * T1a - c1 * T1ab;
    Hx[0][3] = -c1 * T1ab;
    Hx[1][1] = Sb;   Hx[1][2] = -c0 * T1ab;
    Hx[1][3] = Y1b - c0 * T1ab - 2.0 * c1 * T1b;
    Hx[2][2] = -c0 * Y2a + 2.0 * c0 * c0 * T2a + c0 * c1 * T2ab;
    Hx[2][3] = c0 * c1 * T2ab;
    Hx[3][3] = -c1 * Y2b + c0 * c1 * T2ab + 2.0 * c1 * c1 * T2b;
#pragma unroll
    for (int i = 1; i < 4; ++i)
#pragma unroll
      for (int j = 0; j < i; ++j) Hx[i][j] = Hx[j][i];

    double spv[4];
#pragma unroll
    for (int i = 0; i < 4; ++i) spv[i] = sdv[i] * (1.0 - sdv[i]);

    double H[4][5];
#pragma unroll
    for (int i = 0; i < 4; ++i) {
#pragma unroll
      for (int j = 0; j < 4; ++j)
        H[i][j] = sdv[i] * sdv[j] * (Hx[i][j] + (i == j ? mu : 0.0));
      H[i][i] += gxv[i] * spv[i] + 1e-7;
      H[i][4] = -gv[i];
    }
#pragma unroll
    for (int col = 0; col < 4; ++col) {
      double inv = 1.0 / H[col][col];
#pragma unroll
      for (int rr = 0; rr < 4; ++rr) {
        if (rr > col) {
          double f = H[rr][col] * inv;
#pragma unroll
          for (int j = 0; j < 5; ++j) if (j >= col) H[rr][j] -= f * H[col][j];
        }
      }
    }
    double du[4];
#pragma unroll
    for (int i = 3; i >= 0; --i) {
      double s = H[i][4];
#pragma unroll
      for (int j = 0; j < 4; ++j) if (j > i) s -= H[i][j] * du[j];
      du[i] = s / H[i][i];
    }
    double gd = gv[0]*du[0] + gv[1]*du[1] + gv[2]*du[2] + gv[3]*du[3];
    bool bad = !(isfinite(du[0]) && isfinite(du[1]) &&
                 isfinite(du[2]) && isfinite(du[3])) || !(gd < 0.0);
    if (bad) {   // GN fallback (PD)
      double Jxx[4][4];
      Jxx[0][0] = Sa;            Jxx[0][1] = Sab;
      Jxx[0][2] = -c0 * T1a;     Jxx[0][3] = -c1 * T1ab;
      Jxx[1][1] = Sb;            Jxx[1][2] = -c0 * T1ab;  Jxx[1][3] = -c1 * T1b;
      Jxx[2][2] = c0 * c0 * T2a; Jxx[2][3] = c0 * c1 * T2ab;
      Jxx[3][3] = c1 * c1 * T2b;
#pragma unroll
      for (int i = 1; i < 4; ++i)
#pragma unroll
        for (int j = 0; j < i; ++j) Jxx[i][j] = Jxx[j][i];
#pragma unroll
      for (int i = 0; i < 4; ++i) {
#pragma unroll
        for (int j = 0; j < 4; ++j) H[i][j] = sdv[i] * sdv[j] * Jxx[i][j];
        H[i][i] += mu + 1e-7;
        H[i][4] = -gv[i];
      }
#pragma unroll
      for (int col = 0; col < 4; ++col) {
        double inv = 1.0 / H[col][col];
#pragma unroll
        for (int rr = 0; rr < 4; ++rr) {
          if (rr > col) {
            double f = H[rr][col] * inv;
#pragma unroll
            for (int j = 0; j < 5; ++j) if (j >= col) H[rr][j] -= f * H[col][j];
          }
        }
      }
#pragma unroll
      for (int i = 3; i >= 0; --i) {
        double s = H[i][4];
#pragma unroll
        for (int j = 0; j < 4; ++j) if (j > i) s -= H[i][j] * du[j];
        du[i] = s / H[i][i];
      }
      gd = gv[0]*du[0] + gv[1]*du[1] + gv[2]*du[2] + gv[3]*du[3];
      if (!(gd < 0.0)) {
        du[0] = -gv[0]; du[1] = -gv[1]; du[2] = -gv[2]; du[3] = -gv[3];
        gd = -(gv[0]*gv[0] + gv[1]*gv[1] + gv[2]*gv[2] + gv[3]*gv[3]);
      }
    }

    double loss = -2.0*c0*Y0a - 2.0*c1*Y0b
                + c0*c0*Sa + 2.0*c0*c1*Sab + c1*c1*Sb
                + mu * (x0*x0 + x1*x1 + x2*x2 + x3*x3);

    // grind-stopper: Newton decrement below fp64 loss resolution -> converged
    if (!(fabs(gd) > 1e-13 * fabs(loss))) break;

    double nrm = sqrt(du[0]*du[0] + du[1]*du[1] + du[2]*du[2] + du[3]*du[3]);

    // ---- Armijo backtracking with merged 15-moment trial pass ----
    double step = 1.0;
    bool done = false, accepted = false;
    for (int k = 0; k < 25; ++k) {
      double n0 = u0 + step * du[0], n1 = u1 + step * du[1];
      double n2 = u2 + step * du[2], n3 = u3 + step * du[3];
      double c0p = sp_fast(n0), c1p = sp_fast(n1);
      double l0p = sp_fast(n2), l1p = sp_fast(n3);
      double momp[15];
      moments15(l0p, l1p, momp);
      double loss_new = -2.0*c0p*momp[9] - 2.0*c1p*momp[12]
                      + c0p*c0p*momp[0] + 2.0*c0p*c1p*momp[3] + c1p*c1p*momp[6]
                      + mu * (c0p*c0p + c1p*c1p + l0p*l0p + l1p*l1p);
      bool ok = (loss_new <= loss - 1e-4 * step * gd);   // NaN -> reject
      if (ok) {
        u0 = n0; u1 = n1; u2 = n2; u3 = n3;
        x0 = c0p; x1 = c1p; x2 = l0p; x3 = l1p;
#pragma unroll
        for (int j = 0; j < 15; ++j) mom[j] = momp[j];   // reuse as next basis
        if (step * nrm < 1e-9) done = true;
        accepted = true;
        break;
      }
      step *= 0.5;
    }
    if (!accepted) {   // forced exit after 25 halvings
      u0 += step * du[0]; u1 += step * du[1];
      u2 += step * du[2]; u3 += step * du[3];
      x0 = sp_fast(u0); x1 = sp_fast(u1); x2 = sp_fast(u2); x3 = sp_fast(u3);
      moments15(x2, x3, mom);
      if (step * nrm < 1e-9) done = true;
    }
    if (done) break;
  }

  if (lane == 0) {
    bool bad = !(isfinite(x0) && isfinite(x1) && isfinite(x2) && isfinite(x3));
    out[0] = bad ? 50.0f : (float)x0;
    out[1] = bad ? 51.0f : (float)x1;
    out[2] = bad ? 52.0f : (float)x2;
    out[3] = bad ? 53.0f : (float)x3;
  }
}

// ---------------------------------------------------------------- launch
extern "C" void kernel_launch(void* const* d_in, const int* in_sizes, int n_in,
                              void* d_out, int out_size, void* d_ws, size_t ws_size,
                              hipStream_t stream) {
  const float* log_mu = (const float*)d_in[0];
  const float* y      = (const float*)d_in[1];
  const float* t      = (const float*)d_in[2];
  const float* x_init = (const float*)d_in[3];
  float* out = (float*)d_out;
  int n = in_sizes[1];

  const size_t stats_bytes = (size_t)NST * FBINS * sizeof(float);   // 28 KB
  int repl = 0;
  if (d_ws && ws_size >= MAXREPL * stats_bytes) repl = MAXREPL;     // 112 KB
  else if (d_ws && ws_size >= stats_bytes)      repl = 1;

  if (repl > 0) {
    float* stats = (float*)d_ws;
    int nfloats = repl * NST * FBINS;
    zero_stats<<<(nfloats + 255) / 256, 256, 0, stream>>>(stats, nfloats);
    bin_kernel<<<BIN_BLOCKS, BIN_THREADS, 0, stream>>>(y, t, n, stats, repl);
    gn_kernel<false><<<1, 64, 0, stream>>>(stats, repl, nullptr, nullptr, n,
                                           log_mu, x_init, out);
  } else {
    gn_kernel<true><<<1, 64, 0, stream>>>(nullptr, 1, y, t, n,
                                          log_mu, x_init, out);
  }
}

// Round 8
// 120.325 us; speedup vs baseline: 1.7521x; 1.7521x over previous
//
#include <hip/hip_runtime.h>
#include <math.h>

// Binned-sufficient-statistics Newton solver.
//  - bin_kernel: ONE ds_add_u64 per point into 4096 fine bins: packed
//    (count<<32 | round((y+1)*2^14)). LDS-atomic-pipe bound at ~1/7 of the
//    R7 op count.
//  - gn_kernel: 1 block x 64 lanes; 64 fine bins collapsed per lane into
//    4th-order coarse stats (exact delta_f); full-Newton + Armijo with
//    noise-floor + endgame skip (accept Newton step when ||du||<1e-6).

#define FBINS 4096
#define TMAXF 5.0f
#define BIN_BLOCKS  256
#define BIN_THREADS 1024
#define CB    64
#define FPL   (FBINS / CB)     // 64 fine bins per lane
#define YSCALE 16384.0         // 2^14 fixed-point for y+1

// ---------------------------------------------------------------- fast fp64 math
__device__ __forceinline__ double fexp(double x) {
  x = fmin(fmax(x, -708.0), 700.0);
  const double L2E   = 1.4426950408889634074;
  const double LN2HI = 6.93147180369123816490e-01;
  const double LN2LO = 1.90821492927058770002e-10;
  double fn = rint(x * L2E);
  double r  = fma(-fn, LN2HI, x);
  r = fma(-fn, LN2LO, r);
  double p = 2.505210838544172e-8;            // 1/11!
  p = fma(p, r, 2.755731922398589e-7);
  p = fma(p, r, 2.7557319223985893e-6);
  p = fma(p, r, 2.48015873015873e-5);
  p = fma(p, r, 1.984126984126984e-4);
  p = fma(p, r, 1.3888888888888889e-3);
  p = fma(p, r, 8.333333333333333e-3);
  p = fma(p, r, 4.1666666666666664e-2);
  p = fma(p, r, 1.6666666666666666e-1);
  p = fma(p, r, 0.5);
  p = fma(p, r, 1.0);
  p = fma(p, r, 1.0);
  long long n = (long long)fn;
  double s = __longlong_as_double((n + 1023LL) << 52);
  return p * s;
}

__device__ __forceinline__ double flog_ge1(double w) {  // w >= 1
  long long bits = __double_as_longlong(w);
  int k = (int)((bits >> 52) & 0x7FF) - 1023;
  double m = __longlong_as_double((bits & 0xFFFFFFFFFFFFFLL) | 0x3FF0000000000000LL);
  if (m > 1.4142135623730951) { m *= 0.5; k += 1; }
  double t  = (m - 1.0) / (m + 1.0);
  double t2 = t * t;
  double p = 1.0 / 13.0;
  p = fma(p, t2, 1.0 / 11.0);
  p = fma(p, t2, 1.0 / 9.0);
  p = fma(p, t2, 1.0 / 7.0);
  p = fma(p, t2, 0.2);
  p = fma(p, t2, 1.0 / 3.0);
  p = fma(p, t2, 1.0);
  p = 2.0 * t * p;
  return fma((double)k, 6.93147180559945309417e-01, p);
}

__device__ __forceinline__ double sp_fast(double u)  { return flog_ge1(1.0 + fexp(u)); }
__device__ __forceinline__ double sig_fast(double u) { return 1.0 / (1.0 + fexp(-u)); }

__device__ __forceinline__ double bred(double v) {
  for (int m = 1; m < 64; m <<= 1) v += __shfl_xor(v, m, 64);
  return v;
}

// ---------------------------------------------------------------- binning
__global__ void zero_stats(unsigned long long* __restrict__ s, int n) {
  int i = blockIdx.x * blockDim.x + threadIdx.x;
  if (i < n) s[i] = 0ULL;
}

__device__ __forceinline__ void bin_point_u64(unsigned long long* sb, float ti, float yi) {
  int b = (int)(ti * ((float)FBINS / TMAXF));
  b = b < 0 ? 0 : (b > FBINS - 1 ? FBINS - 1 : b);
  unsigned q = __float2uint_rn(fmaxf(yi + 1.0f, 0.0f) * (float)YSCALE);
  atomicAdd(&sb[b], (1ULL << 32) | (unsigned long long)q);
}

__global__ __launch_bounds__(BIN_THREADS)
void bin_kernel(const float* __restrict__ y, const float* __restrict__ t,
                int n, unsigned long long* __restrict__ stats) {
  __shared__ unsigned long long sb[FBINS];   // 32 KB
  for (int i = threadIdx.x; i < FBINS; i += blockDim.x) sb[i] = 0ULL;
  __syncthreads();
  int gtid = blockIdx.x * blockDim.x + threadIdx.x;
  int nt   = gridDim.x * blockDim.x;
  int nv   = n >> 2;
  const float4* t4 = (const float4*)t;
  const float4* y4 = (const float4*)y;
  for (int i = gtid; i < nv; i += nt) {
    float4 tv = t4[i], yv = y4[i];
    bin_point_u64(sb, tv.x, yv.x);
    bin_point_u64(sb, tv.y, yv.y);
    bin_point_u64(sb, tv.z, yv.z);
    bin_point_u64(sb, tv.w, yv.w);
  }
  for (int i = (nv << 2) + gtid; i < n; i += nt) bin_point_u64(sb, t[i], y[i]);
  __syncthreads();
  for (int i = threadIdx.x; i < FBINS; i += blockDim.x) {
    unsigned long long v = sb[i];
    if (v) atomicAdd(&stats[i], v);
  }
}

// ---------------------------------------------------------------- solver
template <bool FUSED>
__global__ __launch_bounds__(64)
void gn_kernel(const unsigned long long* __restrict__ stats_g,
               const float* __restrict__ yv, const float* __restrict__ tv, int n,
               const float* __restrict__ log_mu_p,
               const float* __restrict__ x_init_p,
               float* __restrict__ out) {
  const int lane = threadIdx.x;

  __shared__ unsigned long long sbin[FUSED ? FBINS : 1];
  const unsigned long long* stats = stats_g;
  if (FUSED) {   // safety net only (ws < 32 KB)
    for (int i = lane; i < FBINS; i += 64) sbin[i] = 0ULL;
    __syncthreads();
    for (int i = lane; i < n; i += 64) bin_point_u64(sbin, tv[i], yv[i]);
    __syncthreads();
    stats = sbin;
  }

  // ---- collapse 64 fine bins -> 1 coarse bin per lane (4th-order stats) ----
  const double hf = 5.0 / (double)FBINS;     // exact
  double cn = 0, cb1 = 0, cb2 = 0, cb3 = 0, cb4 = 0;
  double cy = 0, cy1 = 0, cy2 = 0, cy3 = 0;
  const int base = lane * FPL;
#pragma unroll
  for (int i = 0; i < FPL; ++i) {
    unsigned long long v = stats[base + i];
    double nf = (double)(unsigned)(v >> 32);
    double yf = (double)(v & 0xffffffffULL) * (1.0 / YSCALE) - nf;  // sum of y
    double dl  = ((double)i - 31.5) * hf;    // fine center - coarse center, exact
    double dl2 = dl * dl;
    cn  += nf;
    cb1 += nf * dl;
    cb2 += nf * dl2;
    cb3 += nf * dl2 * dl;
    cb4 += nf * dl2 * dl2;
    cy  += yf;
    cy1 += yf * dl;
    cy2 += yf * dl2;
    cy3 += yf * dl2 * dl;
  }
  const double cc = ((double)lane + 0.5) * (5.0 / (double)CB);  // coarse center

  // ---- canary: total count ----
  {
    double tot = bred(cn);
    if (fabs(tot - (double)n) > (double)n * 1e-3 + 1.0) {
      if (lane == 0) for (int j = 0; j < 4; ++j) out[j] = 20.0f + (float)j;
      return;
    }
  }

  // full 15-moment pass at (l0,l1); all lanes end with global sums
  auto moments15 = [&](double l0, double l1, double* mom) {
    double E0 = fexp(-l0 * cc), E1 = fexp(-l1 * cc);
    double AA[3] = {E0 * E0, E0 * E1, E1 * E1};
    double MM[3] = {2.0 * l0, l0 + l1, 2.0 * l1};
#pragma unroll
    for (int q = 0; q < 3; ++q) {
      double m  = MM[q];
      double q0 = cn + m * (-cb1 + m * (0.5 * cb2 + m * (-(1.0/6.0) * cb3 + m * (1.0/24.0) * cb4)));
      double q1 = cb1 + m * (-cb2 + m * (0.5 * cb3 - m * (1.0/6.0) * cb4));
      double q2 = cb2 + m * (-cb3 + m * 0.5 * cb4);
      mom[q * 3 + 0] = AA[q] * q0;
      mom[q * 3 + 1] = AA[q] * (cc * q0 + q1);
      mom[q * 3 + 2] = AA[q] * (cc * (cc * q0 + 2.0 * q1) + q2);
    }
    {
      double r0 = cy + l0 * (-cy1 + l0 * (0.5 * cy2 - l0 * (1.0/6.0) * cy3));
      double r1 = cy1 + l0 * (-cy2 + 0.5 * l0 * cy3);
      double r2 = cy2 - l0 * cy3;
      mom[9]  = E0 * r0;
      mom[10] = E0 * (cc * r0 + r1);
      mom[11] = E0 * (cc * (cc * r0 + 2.0 * r1) + r2);
      r0 = cy + l1 * (-cy1 + l1 * (0.5 * cy2 - l1 * (1.0/6.0) * cy3));
      r1 = cy1 + l1 * (-cy2 + 0.5 * l1 * cy3);
      r2 = cy2 - l1 * cy3;
      mom[12] = E1 * r0;
      mom[13] = E1 * (cc * r0 + r1);
      mom[14] = E1 * (cc * (cc * r0 + 2.0 * r1) + r2);
    }
#pragma unroll
    for (int k = 0; k < 15; ++k) mom[k] = bred(mom[k]);
  };

  // ---- init (all lanes redundantly; uniform) ----
  const double mu = exp((double)log_mu_p[0]);
  double u0, u1, u2, u3;
  {
    double v0 = fmax((double)x_init_p[0], 1e-3);
    double v1 = fmax((double)x_init_p[1], 1e-3);
    double v2 = fmax((double)x_init_p[2], 1e-3);
    double v3 = fmax((double)x_init_p[3], 1e-3);
    u0 = log(exp(v0) - 1.0 + 1e-8);
    u1 = log(exp(v1) - 1.0 + 1e-8);
    u2 = log(exp(v2) - 1.0 + 1e-8);
    u3 = log(exp(v3) - 1.0 + 1e-8);
  }
  double x0 = sp_fast(u0), x1 = sp_fast(u1), x2 = sp_fast(u2), x3 = sp_fast(u3);

  double mom[15];
  moments15(x2, x3, mom);

  for (int iter = 0; iter < 300; ++iter) {
    double Sa = mom[0],  T1a = mom[1],  T2a = mom[2];
    double Sab= mom[3],  T1ab= mom[4],  T2ab= mom[5];
    double Sb = mom[6],  T1b = mom[7],  T2b = mom[8];
    double Y0a= mom[9],  Y1a = mom[10], Y2a = mom[11];
    double Y0b= mom[12], Y1b = mom[13], Y2b = mom[14];

    // ---- Newton system (all lanes redundantly) ----
    double sd0 = sig_fast(u0), sd1 = sig_fast(u1), sd2 = sig_fast(u2), sd3 = sig_fast(u3);
    double c0 = x0, c1 = x1;

    double gx0 = -Y0a + c0 * Sa  + c1 * Sab;
    double gx1 = -Y0b + c0 * Sab + c1 * Sb;
    double gx2 = c0 * (Y1a - c0 * T1a  - c1 * T1ab);
    double gx3 = c1 * (Y1b - c0 * T1ab - c1 * T1b);

    double sdv[4] = {sd0, sd1, sd2, sd3};
    double gxv[4] = {gx0 + mu * x0, gx1 + mu * x1, gx2 + mu * x2, gx3 + mu * x3};
    double gv[4];
#pragma unroll
    for (int i = 0; i < 4; ++i) gv[i] = gxv[i] * sdv[i];

    double Hx[4][4];
    Hx[0][0] = Sa;   Hx[0][1] = Sab;
    Hx[0][2] = Y1a - 2.0 * c0 * T1a - c1 * T1ab;
    Hx[0][3] = -c1 * T1ab;
    Hx[1][1] = Sb;   Hx[1][2] = -c0 * T1ab;
    Hx[1][3] = Y1b - c0 * T1ab - 2.0 * c1 * T1b;
    Hx[2][2] = -c0 * Y2a + 2.0 * c0 * c0 * T2a + c0 * c1 * T2ab;
    Hx[2][3] = c0 * c1 * T2ab;
    Hx[3][3] = -c1 * Y2b + c0 * c1 * T2ab + 2.0 * c1 * c1 * T2b;
#pragma unroll
    for (int i = 1; i < 4; ++i)
#pragma unroll
      for (int j = 0; j < i; ++j) Hx[i][j] = Hx[j][i];

    double spv[4];
#pragma unroll
    for (int i = 0; i < 4; ++i) spv[i] = sdv[i] * (1.0 - sdv[i]);

    double H[4][5];
#pragma unroll
    for (int i = 0; i < 4; ++i) {
#pragma unroll
      for (int j = 0; j < 4; ++j)
        H[i][j] = sdv[i] * sdv[j] * (Hx[i][j] + (i == j ? mu : 0.0));
      H[i][i] += gxv[i] * spv[i] + 1e-7;
      H[i][4] = -gv[i];
    }
#pragma unroll
    for (int col = 0; col < 4; ++col) {
      double inv = 1.0 / H[col][col];
#pragma unroll
      for (int rr = 0; rr < 4; ++rr) {
        if (rr > col) {
          double f = H[rr][col] * inv;
#pragma unroll
          for (int j = 0; j < 5; ++j) if (j >= col) H[rr][j] -= f * H[col][j];
        }
      }
    }
    double du[4];
#pragma unroll
    for (int i = 3; i >= 0; --i) {
      double s = H[i][4];
#pragma unroll
      for (int j = 0; j < 4; ++j) if (j > i) s -= H[i][j] * du[j];
      du[i] = s / H[i][i];
    }
    double gd = gv[0]*du[0] + gv[1]*du[1] + gv[2]*du[2] + gv[3]*du[3];
    bool bad = !(isfinite(du[0]) && isfinite(du[1]) &&
                 isfinite(du[2]) && isfinite(du[3])) || !(gd < 0.0);
    if (bad) {   // GN fallback (PD)
      double Jxx[4][4];
      Jxx[0][0] = Sa;            Jxx[0][1] = Sab;
      Jxx[0][2] = -c0 * T1a;     Jxx[0][3] = -c1 * T1ab;
      Jxx[1][1] = Sb;            Jxx[1][2] = -c0 * T1ab;  Jxx[1][3] = -c1 * T1b;
      Jxx[2][2] = c0 * c0 * T2a; Jxx[2][3] = c0 * c1 * T2ab;
      Jxx[3][3] = c1 * c1 * T2b;
#pragma unroll
      for (int i = 1; i < 4; ++i)
#pragma unroll
        for (int j = 0; j < i; ++j) Jxx[i][j] = Jxx[j][i];
#pragma unroll
      for (int i = 0; i < 4; ++i) {
#pragma unroll
        for (int j = 0; j < 4; ++j) H[i][j] = sdv[i] * sdv[j] * Jxx[i][j];
        H[i][i] += mu + 1e-7;
        H[i][4] = -gv[i];
      }
#pragma unroll
      for (int col = 0; col < 4; ++col) {
        double inv = 1.0 / H[col][col];
#pragma unroll
        for (int rr = 0; rr < 4; ++rr) {
          if (rr > col) {
            double f = H[rr][col] * inv;
#pragma unroll
            for (int j = 0; j < 5; ++j) if (j >= col) H[rr][j] -= f * H[col][j];
          }
        }
      }
#pragma unroll
      for (int i = 3; i >= 0; --i) {
        double s = H[i][4];
#pragma unroll
        for (int j = 0; j < 4; ++j) if (j > i) s -= H[i][j] * du[j];
        du[i] = s / H[i][i];
      }
      gd = gv[0]*du[0] + gv[1]*du[1] + gv[2]*du[2] + gv[3]*du[3];
      if (!(gd < 0.0)) {
        du[0] = -gv[0]; du[1] = -gv[1]; du[2] = -gv[2]; du[3] = -gv[3];
        gd = -(gv[0]*gv[0] + gv[1]*gv[1] + gv[2]*gv[2] + gv[3]*gv[3]);
      }
    }

    double loss = -2.0*c0*Y0a - 2.0*c1*Y0b
                + c0*c0*Sa + 2.0*c0*c1*Sab + c1*c1*Sb
                + mu * (x0*x0 + x1*x1 + x2*x2 + x3*x3);

    // grind-stopper: Newton decrement below fp64 loss resolution -> converged
    if (!(fabs(gd) > 1e-13 * fabs(loss))) break;

    double nrm = sqrt(du[0]*du[0] + du[1]*du[1] + du[2]*du[2] + du[3]*du[3]);

    // ---- endgame: tiny Newton step is certainly fine; skip line search ----
    if (nrm < 1e-6) {
      u0 += du[0]; u1 += du[1]; u2 += du[2]; u3 += du[3];
      x0 = sp_fast(u0); x1 = sp_fast(u1); x2 = sp_fast(u2); x3 = sp_fast(u3);
      if (nrm < 1e-9) break;
      moments15(x2, x3, mom);
      continue;
    }

    // ---- Armijo backtracking with merged 15-moment trial pass ----
    double slack = 1e-11 * fabs(loss);   // fp64/fexp noise floor
    double step = 1.0;
    bool done = false, accepted = false;
    for (int k = 0; k < 25; ++k) {
      double n0 = u0 + step * du[0], n1 = u1 + step * du[1];
      double n2 = u2 + step * du[2], n3 = u3 + step * du[3];
      double c0p = sp_fast(n0), c1p = sp_fast(n1);
      double l0p = sp_fast(n2), l1p = sp_fast(n3);
      double momp[15];
      moments15(l0p, l1p, momp);
      double loss_new = -2.0*c0p*momp[9] - 2.0*c1p*momp[12]
                      + c0p*c0p*momp[0] + 2.0*c0p*c1p*momp[3] + c1p*c1p*momp[6]
                      + mu * (c0p*c0p + c1p*c1p + l0p*l0p + l1p*l1p);
      bool ok = (loss_new <= loss - 1e-4 * step * gd + slack);   // NaN -> reject
      if (ok) {
        u0 = n0; u1 = n1; u2 = n2; u3 = n3;
        x0 = c0p; x1 = c1p; x2 = l0p; x3 = l1p;
#pragma unroll
        for (int j = 0; j < 15; ++j) mom[j] = momp[j];   // reuse as next basis
        if (step * nrm < 1e-9) done = true;
        accepted = true;
        break;
      }
      step *= 0.5;
    }
    if (!accepted) {   // forced exit after 25 halvings
      u0 += step * du[0]; u1 += step * du[1];
      u2 += step * du[2]; u3 += step * du[3];
      x0 = sp_fast(u0); x1 = sp_fast(u1); x2 = sp_fast(u2); x3 = sp_fast(u3);
      moments15(x2, x3, mom);
      if (step * nrm < 1e-9) done = true;
    }
    if (done) break;
  }

  if (lane == 0) {
    bool bad = !(isfinite(x0) && isfinite(x1) && isfinite(x2) && isfinite(x3));
    out[0] = bad ? 50.0f : (float)x0;
    out[1] = bad ? 51.0f : (float)x1;
    out[2] = bad ? 52.0f : (float)x2;
    out[3] = bad ? 53.0f : (float)x3;
  }
}

// ---------------------------------------------------------------- launch
extern "C" void kernel_launch(void* const* d_in, const int* in_sizes, int n_in,
                              void* d_out, int out_size, void* d_ws, size_t ws_size,
                              hipStream_t stream) {
  const float* log_mu = (const float*)d_in[0];
  const float* y      = (const float*)d_in[1];
  const float* t      = (const float*)d_in[2];
  const float* x_init = (const float*)d_in[3];
  float* out = (float*)d_out;
  int n = in_sizes[1];

  const size_t stats_bytes = (size_t)FBINS * sizeof(unsigned long long);  // 32 KB
  if (d_ws && ws_size >= stats_bytes) {
    unsigned long long* stats = (unsigned long long*)d_ws;
    zero_stats<<<(FBINS + 255) / 256, 256, 0, stream>>>(stats, FBINS);
    bin_kernel<<<BIN_BLOCKS, BIN_THREADS, 0, stream>>>(y, t, n, stats);
    gn_kernel<false><<<1, 64, 0, stream>>>(stats, nullptr, nullptr, n,
                                           log_mu, x_init, out);
  } else {
    gn_kernel<true><<<1, 64, 0, stream>>>(nullptr, y, t, n,
                                          log_mu, x_init, out);
  }
}